// Round 4
// baseline (215.066 us; speedup 1.0000x reference)
//
#include <hip/hip_runtime.h>
#include <hip/hip_bf16.h>
#include <math.h>

#define T_TOK  16384
#define H_DIM  512
#define NHEADS 12
#define E_DIM  768
#define EPS_N  1e-5f
#define QK_SCALE 0.04419417382415922f

typedef unsigned short u16;
typedef __bf16 bf16;
typedef bf16   bf16x8 __attribute__((ext_vector_type(8)));
typedef float  f32x4  __attribute__((ext_vector_type(4)));
typedef u16    u16x4  __attribute__((ext_vector_type(4)));
typedef u16    u16x8  __attribute__((ext_vector_type(8)));

__device__ __forceinline__ u16 f2bf(float f) {
  unsigned u = __builtin_bit_cast(unsigned, f);
  unsigned r = u + 0x7fffu + ((u >> 16) & 1u);
  return (u16)(r >> 16);
}
__device__ __forceinline__ float bf2f(u16 h) {
  unsigned u = ((unsigned)h) << 16;
  return __builtin_bit_cast(float, u);
}
__device__ __forceinline__ float wave_sum(float v) {
  #pragma unroll
  for (int off = 32; off; off >>= 1) v += __shfl_xor(v, off, 64);
  return v;
}

// ---------------- Kernel A: gather embedding rows, cast to bf16 -------------
__global__ __launch_bounds__(256) void gather_emb(
    const int* __restrict__ hash_ids, const int* __restrict__ offsets,
    const float* __restrict__ emb_w, u16* __restrict__ emb) {
  int idx = blockIdx.x * 256 + threadIdx.x;        // T*12*8
  int pair = idx >> 3;                             // t*12 + head
  int sub = idx & 7;
  int t = pair / 12;
  int head = pair - t * 12;
  int row = hash_ids[pair] + offsets[head];
  const float* src = emb_w + (size_t)row * 64 + sub * 8;
  float4 a = *(const float4*)src;
  float4 b = *(const float4*)(src + 4);
  u16x8 o;
  o[0] = f2bf(a.x); o[1] = f2bf(a.y); o[2] = f2bf(a.z); o[3] = f2bf(a.w);
  o[4] = f2bf(b.x); o[5] = f2bf(b.y); o[6] = f2bf(b.z); o[7] = f2bf(b.w);
  *(u16x8*)(emb + (size_t)t * E_DIM + head * 64 + sub * 8) = o;
}

// ---------------- Kernel A2: build WcatT (2560 x 768) bf16 ------------------
__global__ __launch_bounds__(256) void build_wcat(
    const float* __restrict__ kp, const float* __restrict__ vp,
    u16* __restrict__ wt) {
  __shared__ float tile[32][33];
  int m = blockIdx.z;
  const float* src = (m < 4) ? (kp + (size_t)m * E_DIM * H_DIM) : vp;
  int h0 = blockIdx.x * 32, e0 = blockIdx.y * 32;
  int tx = threadIdx.x, ty = threadIdx.y;          // block (32,8)
  #pragma unroll
  for (int j = 0; j < 32; j += 8)
    tile[ty + j][tx] = src[(size_t)(e0 + ty + j) * H_DIM + h0 + tx];
  __syncthreads();
  #pragma unroll
  for (int j = 0; j < 32; j += 8) {
    int h = h0 + ty + j, e = e0 + tx;
    wt[(size_t)(m * H_DIM + h) * E_DIM + e] = f2bf(tile[tx][ty + j]);
  }
}

// ---------------- Kernel A3: fold conv_norm_w into conv weights -------------
__global__ __launch_bounds__(256) void build_wc(
    const float* __restrict__ conv_w, const float* __restrict__ cnw,
    float* __restrict__ wc) {
  int cf = blockIdx.x * 256 + threadIdx.x;         // 2048
  float c = cnw[cf];
  #pragma unroll
  for (int k = 0; k < 4; ++k) wc[k * 2048 + cf] = conv_w[cf * 4 + k] * c;
}

// ---------------- Kernel A4: prep q — fold qw, permute to frag layout -------
// qhp[t*2048 + (c>>6)*64 + (c&15)*4 + ((c>>4)&3)] = bf16(hidden[t,c]*qw[c])
// qssA[t*4+g] = sum_{c in g} hidden[t,c]^2
__global__ __launch_bounds__(256) void prep_q(
    const float* __restrict__ hidden, const float* __restrict__ qw,
    u16* __restrict__ qhp, float* __restrict__ qssA) {
  int t = blockIdx.x;
  int g = threadIdx.x >> 6;                        // wave -> group
  int lane = threadIdx.x & 63;
  int sg = lane >> 4, lr = lane & 15;
  float q2 = 0.f;
  #pragma unroll
  for (int bb = 0; bb < 2; ++bb) {
    int b = g * 8 + sg + bb * 4;                   // 64-col block index
    const float* hp = hidden + (size_t)t * 2048 + b * 64 + lr;
    u16x4 o;
    #pragma unroll
    for (int n = 0; n < 4; ++n) {
      float q = hp[n * 16];
      float w = qw[b * 64 + n * 16 + lr];
      q2 += q * q;
      o[n] = f2bf(q * w);
    }
    *(u16x4*)(qhp + (size_t)t * 2048 + b * 64 + lr * 4) = o;
  }
  q2 = wave_sum(q2);
  if (lane == 0) qssA[t * 4 + g] = q2;
}

// ---------------- Kernel B: GEMM + fused k-side reduction epilogue ----------
// C = A(16384x768) * BT^T. bx<16: key quarter (g=bx>>2,q=bx&3) -> reduce
// k^2 and qh*(k*kw) per row, store per-(t,g,q) partials; keys never stored.
// bx>=16: vraw quarter -> store V bf16 + per-row v^2 partial.
__global__ __launch_bounds__(256, 2) void gemm_bf16(
    const u16* __restrict__ A, const u16* __restrict__ BT,
    const u16* __restrict__ qhp, const float* __restrict__ kw,
    u16* __restrict__ V, float* __restrict__ kssP, float* __restrict__ qkP,
    float* __restrict__ msvP) {
  __shared__ u16 As[128][64];
  __shared__ u16 Bs[128][64];
  __shared__ float part[2][128][2];
  const int K = E_DIM;
  int tid = threadIdx.x;
  int lane = tid & 63, wid = tid >> 6;
  int bx = blockIdx.x, by = blockIdx.y;
  int wm = (wid >> 1) * 64, wn = (wid & 1) * 64;
  int widN = wid & 1;
  int lr16 = lane & 15, rgrp = lane >> 4;

  const u16* aptr = A + (size_t)(by * 128 + (tid >> 3)) * K + (tid & 7) * 8;
  const u16* bptr = BT + (size_t)(bx * 128 + (tid >> 3)) * K + (tid & 7) * 8;
  int lds_off = tid * 16;

  // ---- prefetch q fragments + kw before the K-loop (key tiles only) ----
  u16x4 qf[4][4];
  float kwv[4];
  if (bx < 16) {
    int g = bx >> 2, qq = bx & 3;
    int cb = (g * 8 + qq * 2 + (wn >> 6)) * 64 + lr16 * 4;
    #pragma unroll
    for (int m = 0; m < 4; ++m)
      #pragma unroll
      for (int j = 0; j < 4; ++j)
        qf[m][j] = *(const u16x4*)(qhp +
            (size_t)(by * 128 + wm + m * 16 + rgrp * 4 + j) * 2048 + cb);
    int colbase = g * 512 + qq * 128 + wn + lr16;
    #pragma unroll
    for (int n = 0; n < 4; ++n) kwv[n] = kw[colbase + n * 16];
  }

  f32x4 acc[4][4] = {};

  for (int k0 = 0; k0 < K; k0 += 64) {
    #pragma unroll
    for (int r = 0; r < 4; ++r) {
      __builtin_amdgcn_global_load_lds(
        (const __attribute__((address_space(1))) void*)(aptr + (size_t)(r * 32) * K + k0),
        (__attribute__((address_space(3))) void*)((char*)&As[0][0] + r * 4096 + lds_off),
        16, 0, 0);
      __builtin_amdgcn_global_load_lds(
        (const __attribute__((address_space(1))) void*)(bptr + (size_t)(r * 32) * K + k0),
        (__attribute__((address_space(3))) void*)((char*)&Bs[0][0] + r * 4096 + lds_off),
        16, 0, 0);
    }
    __syncthreads();
    int lk8 = (lane >> 4) * 8;
    #pragma unroll
    for (int kk = 0; kk < 2; ++kk) {
      bf16x8 af[4], bfv[4];
      #pragma unroll
      for (int m = 0; m < 4; ++m)
        af[m] = *reinterpret_cast<const bf16x8*>(&As[wm + m * 16 + lr16][kk * 32 + lk8]);
      #pragma unroll
      for (int n = 0; n < 4; ++n)
        bfv[n] = *reinterpret_cast<const bf16x8*>(&Bs[wn + n * 16 + lr16][kk * 32 + lk8]);
      #pragma unroll
      for (int m = 0; m < 4; ++m)
        #pragma unroll
        for (int n = 0; n < 4; ++n)
          acc[m][n] = __builtin_amdgcn_mfma_f32_16x16x32_bf16(af[m], bfv[n], acc[m][n], 0, 0, 0);
    }
    __syncthreads();
  }

  if (bx < 16) {
    // ---- key tile: fused reductions from registers ----
    int g = bx >> 2, qq = bx & 3;
    #pragma unroll
    for (int m = 0; m < 4; ++m) {
      #pragma unroll
      for (int j = 0; j < 4; ++j) {
        int r = wm + m * 16 + rgrp * 4 + j;        // block-local row
        float sk2 = 0.f, sqk = 0.f;
        #pragma unroll
        for (int n = 0; n < 4; ++n) {
          float kv = acc[m][n][j];
          float qv = bf2f(qf[m][j][n]);
          sk2 += kv * kv;
          sqk += qv * (kv * kwv[n]);
        }
        #pragma unroll
        for (int off = 1; off < 16; off <<= 1) {
          sk2 += __shfl_xor(sk2, off, 64);
          sqk += __shfl_xor(sqk, off, 64);
        }
        if (lr16 == 0) {
          part[widN][r][0] = sk2;
          part[widN][r][1] = sqk;
        }
      }
    }
    __syncthreads();
    if (tid < 128) {
      int t = by * 128 + tid;
      int o = (t * 4 + g) * 4 + qq;
      kssP[o] = part[0][tid][0] + part[1][tid][0];
      qkP[o]  = part[0][tid][1] + part[1][tid][1];
    }
  } else {
    // ---- vraw tile: store bf16 V + per-row v^2 partial ----
    int q2i = bx - 16;
    #pragma unroll
    for (int m = 0; m < 4; ++m) {
      #pragma unroll
      for (int j = 0; j < 4; ++j) {
        int r = wm + m * 16 + rgrp * 4 + j;
        size_t t = (size_t)(by * 128 + r);
        float sv2 = 0.f;
        #pragma unroll
        for (int n = 0; n < 4; ++n) {
          float v = acc[m][n][j];
          sv2 += v * v;
          V[t * 512 + q2i * 128 + wn + n * 16 + lr16] = f2bf(v);
        }
        #pragma unroll
        for (int off = 1; off < 16; off <<= 1) sv2 += __shfl_xor(sv2, off, 64);
        if (lr16 == 0) part[widN][r][0] = sv2;
      }
    }
    __syncthreads();
    if (tid < 128) {
      int t = by * 128 + tid;
      msvP[t * 4 + q2i] = part[0][tid][0] + part[1][tid][0];
    }
  }
}

// ---------------- Kernel C1: finish gates from partials ---------------------
__global__ __launch_bounds__(256) void gate_finish(
    const float* __restrict__ kssP, const float* __restrict__ qkP,
    const float* __restrict__ qssA, const float* __restrict__ msvP,
    float* __restrict__ gateA, float* __restrict__ aA) {
  int i = blockIdx.x * 256 + threadIdx.x;          // T*4
  int t = i >> 2;
  float4 k4 = *(const float4*)&kssP[i * 4];
  float4 d4 = *(const float4*)&qkP[i * 4];
  float4 m4 = *(const float4*)&msvP[t * 4];
  float kss = k4.x + k4.y + k4.z + k4.w;
  float qk  = d4.x + d4.y + d4.z + d4.w;
  float qss = qssA[i];
  float msv = (m4.x + m4.y + m4.z + m4.w) * (1.0f / 512.0f);
  float qinv = rsqrtf(qss * (1.0f / 512.0f) + EPS_N);
  float kinv = rsqrtf(kss * (1.0f / 512.0f) + EPS_N);
  float gate = 1.0f / (1.0f + __expf(-qk * qinv * kinv * QK_SCALE));
  gateA[i] = gate;
  aA[i] = gate * rsqrtf(gate * gate * msv + EPS_N);
}

// ---------------- Kernel C2: value + dilated conv + silu + write out --------
__global__ __launch_bounds__(256) void out_kernel(
    const u16* __restrict__ V,          // (T,512) bf16
    const float* __restrict__ gateA, const float* __restrict__ aA,
    const float* __restrict__ wc,       // [4][2048]
    float* __restrict__ out) {
  int idx = blockIdx.x * 256 + threadIdx.x;  // T*256 threads, 8 ch each
  int t = idx >> 8;
  int c8 = (idx & 255) * 8;
  int g = c8 >> 9;
  int h = c8 & 511;

  float acc[8] = {0.f, 0.f, 0.f, 0.f, 0.f, 0.f, 0.f, 0.f};
  float vr_t[8];
  #pragma unroll
  for (int k = 0; k < 4; ++k) {
    int tk = t - 12 + 4 * k;
    if (tk < 0) continue;
    float s = aA[tk * 4 + g];
    u16x8 vv = *(const u16x8*)&V[(size_t)tk * 512 + h];
    float4 w0 = *(const float4*)(wc + k * 2048 + c8);
    float4 w1 = *(const float4*)(wc + k * 2048 + c8 + 4);
    float w8[8] = {w0.x, w0.y, w0.z, w0.w, w1.x, w1.y, w1.z, w1.w};
    #pragma unroll
    for (int j = 0; j < 8; ++j) {
      float v = bf2f(vv[j]);
      acc[j] += w8[j] * s * v;
      if (k == 3) vr_t[j] = v;
    }
  }
  float gate = gateA[t * 4 + g];
  float r[8];
  #pragma unroll
  for (int j = 0; j < 8; ++j) {
    float y = acc[j];
    r[j] = gate * vr_t[j] + y / (1.0f + __expf(-y));
  }
  float* op = out + (size_t)t * 2048 + c8;
  *(float4*)op       = make_float4(r[0], r[1], r[2], r[3]);
  *(float4*)(op + 4) = make_float4(r[4], r[5], r[6], r[7]);
}

extern "C" void kernel_launch(void* const* d_in, const int* in_sizes, int n_in,
                              void* d_out, int out_size, void* d_ws, size_t ws_size,
                              hipStream_t stream) {
  const int*   hash_ids = (const int*)d_in[0];
  const int*   offsets  = (const int*)d_in[1];
  const float* emb_w    = (const float*)d_in[2];
  const float* kp       = (const float*)d_in[3];
  const float* qw       = (const float*)d_in[4];
  const float* kw       = (const float*)d_in[5];
  const float* vp       = (const float*)d_in[6];
  const float* conv_w   = (const float*)d_in[7];
  const float* cw       = (const float*)d_in[8];
  const float* hidden   = (const float*)d_in[9];
  float* out = (float*)d_out;
  char*  ws  = (char*)d_ws;

  u16*   V     = (u16*)ws;                       // 16,777,216
  u16*   emb   = (u16*)(ws + 16777216);          // 25,165,824
  u16*   wt    = (u16*)(ws + 41943040);          //  3,932,160
  u16*   qhp   = (u16*)(ws + 45875200);          // 67,108,864
  float* kssP  = (float*)(ws + 112984064);       //  1,048,576
  float* qkP   = (float*)(ws + 114032640);       //  1,048,576
  float* qssA  = (float*)(ws + 115081216);       //    262,144
  float* msvP  = (float*)(ws + 115343360);       //    262,144
  float* gateA = (float*)(ws + 115605504);       //    262,144
  float* aA    = (float*)(ws + 115867648);       //    262,144
  float* wc    = (float*)(ws + 116129792);       //     32,768

  gather_emb<<<(T_TOK * 12 * 8) / 256, 256, 0, stream>>>(hash_ids, offsets, emb_w, emb);
  build_wcat<<<dim3(16, 24, 5), dim3(32, 8), 0, stream>>>(kp, vp, wt);
  build_wc<<<8, 256, 0, stream>>>(conv_w, cw, wc);
  prep_q<<<T_TOK, 256, 0, stream>>>(hidden, qw, qhp, qssA);
  gemm_bf16<<<dim3(20, 128), 256, 0, stream>>>(emb, wt, qhp, kw,
                                               V, kssP, qkP, msvP);
  gate_finish<<<(T_TOK * 4) / 256, 256, 0, stream>>>(kssP, qkP, qssA, msvP, gateA, aA);
  out_kernel<<<T_TOK * 256 / 256, 256, 0, stream>>>(V, gateA, aA, wc, out);
}

// Round 5
// 205.356 us; speedup vs baseline: 1.0473x; 1.0473x over previous
//
#include <hip/hip_runtime.h>
#include <hip/hip_bf16.h>
#include <math.h>

#define T_TOK  16384
#define H_DIM  512
#define NHEADS 12
#define E_DIM  768
#define EPS_N  1e-5f
#define QK_SCALE 0.04419417382415922f

typedef unsigned short u16;
typedef __bf16 bf16;
typedef bf16   bf16x8 __attribute__((ext_vector_type(8)));
typedef float  f32x4  __attribute__((ext_vector_type(4)));
typedef u16    u16x4  __attribute__((ext_vector_type(4)));
typedef u16    u16x8  __attribute__((ext_vector_type(8)));

__device__ __forceinline__ u16 f2bf(float f) {
  unsigned u = __builtin_bit_cast(unsigned, f);
  unsigned r = u + 0x7fffu + ((u >> 16) & 1u);
  return (u16)(r >> 16);
}
__device__ __forceinline__ float bf2f(u16 h) {
  unsigned u = ((unsigned)h) << 16;
  return __builtin_bit_cast(float, u);
}
__device__ __forceinline__ float wave_sum(float v) {
  #pragma unroll
  for (int off = 32; off; off >>= 1) v += __shfl_xor(v, off, 64);
  return v;
}

// ---------------- Kernel A: gather embedding rows, cast to bf16 -------------
__global__ __launch_bounds__(256) void gather_emb(
    const int* __restrict__ hash_ids, const int* __restrict__ offsets,
    const float* __restrict__ emb_w, u16* __restrict__ emb) {
  int idx = blockIdx.x * 256 + threadIdx.x;        // T*12*8
  int pair = idx >> 3;                             // t*12 + head
  int sub = idx & 7;
  int t = pair / 12;
  int head = pair - t * 12;
  int row = hash_ids[pair] + offsets[head];
  const float* src = emb_w + (size_t)row * 64 + sub * 8;
  float4 a = *(const float4*)src;
  float4 b = *(const float4*)(src + 4);
  u16x8 o;
  o[0] = f2bf(a.x); o[1] = f2bf(a.y); o[2] = f2bf(a.z); o[3] = f2bf(a.w);
  o[4] = f2bf(b.x); o[5] = f2bf(b.y); o[6] = f2bf(b.z); o[7] = f2bf(b.w);
  *(u16x8*)(emb + (size_t)t * E_DIM + head * 64 + sub * 8) = o;
}

// ---------------- Kernel A2: build WcatT (2560 x 768) bf16 ------------------
__global__ __launch_bounds__(256) void build_wcat(
    const float* __restrict__ kp, const float* __restrict__ vp,
    u16* __restrict__ wt) {
  __shared__ float tile[32][33];
  int m = blockIdx.z;
  const float* src = (m < 4) ? (kp + (size_t)m * E_DIM * H_DIM) : vp;
  int h0 = blockIdx.x * 32, e0 = blockIdx.y * 32;
  int tx = threadIdx.x, ty = threadIdx.y;          // block (32,8)
  #pragma unroll
  for (int j = 0; j < 32; j += 8)
    tile[ty + j][tx] = src[(size_t)(e0 + ty + j) * H_DIM + h0 + tx];
  __syncthreads();
  #pragma unroll
  for (int j = 0; j < 32; j += 8) {
    int h = h0 + ty + j, e = e0 + tx;
    wt[(size_t)(m * H_DIM + h) * E_DIM + e] = f2bf(tile[tx][ty + j]);
  }
}

// ---------------- Kernel A3: fold conv_norm_w into conv w; qw*kw ------------
__global__ __launch_bounds__(256) void build_wc(
    const float* __restrict__ conv_w, const float* __restrict__ cnw,
    const float* __restrict__ qw, const float* __restrict__ kw,
    float* __restrict__ wc, float* __restrict__ qwkw) {
  int cf = blockIdx.x * 256 + threadIdx.x;         // 2048
  float c = cnw[cf];
  #pragma unroll
  for (int k = 0; k < 4; ++k) wc[k * 2048 + cf] = conv_w[cf * 4 + k] * c;
  qwkw[cf] = qw[cf] * kw[cf];
}

// ---------------- Kernel A4: prep q (vectorized, LDS permute) ---------------
// qhp[t*2048 + (c>>6)*64 + (c&15)*4 + ((c>>4)&3)] = bf16(hidden[t,c]*qw[c]*kw[c])
// qssA[t*4+g] = sum_{c in group g} hidden[t,c]^2   (fp32)
__global__ __launch_bounds__(256) void prep_q(
    const float* __restrict__ hidden, const float* __restrict__ qwkw,
    u16* __restrict__ qhp, float* __restrict__ qssA) {
  __shared__ u16 qs[32 * 72];                      // 72-stride pad: 2-way banks
  int t = blockIdx.x, tid = threadIdx.x;
  int b = tid >> 3;                                // 64-col block 0..31
  int c0 = tid * 8;
  const float* hp = hidden + (size_t)t * 2048 + c0;
  float4 a0 = *(const float4*)hp;
  float4 a1 = *(const float4*)(hp + 4);
  float4 w0 = *(const float4*)(qwkw + c0);
  float4 w1 = *(const float4*)(qwkw + c0 + 4);
  float q[8] = {a0.x, a0.y, a0.z, a0.w, a1.x, a1.y, a1.z, a1.w};
  float w[8] = {w0.x, w0.y, w0.z, w0.w, w1.x, w1.y, w1.z, w1.w};
  float q2 = 0.f;
  u16x8 v;
  #pragma unroll
  for (int j = 0; j < 8; ++j) { q2 += q[j] * q[j]; v[j] = f2bf(q[j] * w[j]); }
  *(u16x8*)&qs[b * 72 + (c0 & 63)] = v;
  q2 = wave_sum(q2);
  if ((tid & 63) == 0) qssA[t * 4 + (tid >> 6)] = q2;
  __syncthreads();
  // output slots o = c0..c0+7 (permuted layout), gather from LDS
  int r0 = (c0 & 63) >> 2;                         // base slot>>2
  u16x8 o;
  #pragma unroll
  for (int half = 0; half < 2; ++half)
    #pragma unroll
    for (int j = 0; j < 4; ++j)
      o[half * 4 + j] = qs[b * 72 + j * 16 + r0 + half];
  *(u16x8*)(qhp + (size_t)t * 2048 + c0) = o;
}

// ---------------- Kernel B: GEMM + fused k-side reduction epilogue ----------
__global__ __launch_bounds__(256, 2) void gemm_bf16(
    const u16* __restrict__ A, const u16* __restrict__ BT,
    const u16* __restrict__ qhp,
    u16* __restrict__ V, float* __restrict__ kssP, float* __restrict__ qkP,
    float* __restrict__ msvP) {
  __shared__ u16 As[128][64];
  __shared__ u16 Bs[128][64];
  __shared__ float part[2][128][2];
  const int K = E_DIM;
  int tid = threadIdx.x;
  int lane = tid & 63, wid = tid >> 6;
  int bx = blockIdx.x, by = blockIdx.y;
  int wm = (wid >> 1) * 64, wn = (wid & 1) * 64;
  int widN = wid & 1;
  int lr16 = lane & 15, rgrp = lane >> 4;

  const u16* aptr = A + (size_t)(by * 128 + (tid >> 3)) * K + (tid & 7) * 8;
  const u16* bptr = BT + (size_t)(bx * 128 + (tid >> 3)) * K + (tid & 7) * 8;
  int lds_off = tid * 16;

  f32x4 acc[4][4] = {};

  for (int k0 = 0; k0 < K; k0 += 64) {
    #pragma unroll
    for (int r = 0; r < 4; ++r) {
      __builtin_amdgcn_global_load_lds(
        (const __attribute__((address_space(1))) void*)(aptr + (size_t)(r * 32) * K + k0),
        (__attribute__((address_space(3))) void*)((char*)&As[0][0] + r * 4096 + lds_off),
        16, 0, 0);
      __builtin_amdgcn_global_load_lds(
        (const __attribute__((address_space(1))) void*)(bptr + (size_t)(r * 32) * K + k0),
        (__attribute__((address_space(3))) void*)((char*)&Bs[0][0] + r * 4096 + lds_off),
        16, 0, 0);
    }
    __syncthreads();
    int lk8 = (lane >> 4) * 8;
    #pragma unroll
    for (int kk = 0; kk < 2; ++kk) {
      bf16x8 af[4], bfv[4];
      #pragma unroll
      for (int m = 0; m < 4; ++m)
        af[m] = *reinterpret_cast<const bf16x8*>(&As[wm + m * 16 + lr16][kk * 32 + lk8]);
      #pragma unroll
      for (int n = 0; n < 4; ++n)
        bfv[n] = *reinterpret_cast<const bf16x8*>(&Bs[wn + n * 16 + lr16][kk * 32 + lk8]);
      #pragma unroll
      for (int m = 0; m < 4; ++m)
        #pragma unroll
        for (int n = 0; n < 4; ++n)
          acc[m][n] = __builtin_amdgcn_mfma_f32_16x16x32_bf16(af[m], bfv[n], acc[m][n], 0, 0, 0);
    }
    __syncthreads();
  }

  if (bx < 16) {
    // ---- key tile: load q fragments NOW (epilogue), then fused reductions --
    int g = bx >> 2, qq = bx & 3;
    int cb = (g * 8 + qq * 2 + (wn >> 6)) * 64 + lr16 * 4;
    u16x4 qf[4][4];
    #pragma unroll
    for (int m = 0; m < 4; ++m)
      #pragma unroll
      for (int j = 0; j < 4; ++j)
        qf[m][j] = *(const u16x4*)(qhp +
            (size_t)(by * 128 + wm + m * 16 + rgrp * 4 + j) * 2048 + cb);
    #pragma unroll
    for (int m = 0; m < 4; ++m) {
      #pragma unroll
      for (int j = 0; j < 4; ++j) {
        int r = wm + m * 16 + rgrp * 4 + j;        // block-local row
        float sk2 = 0.f, sqk = 0.f;
        #pragma unroll
        for (int n = 0; n < 4; ++n) {
          float kv = acc[m][n][j];
          sk2 += kv * kv;
          sqk += bf2f(qf[m][j][n]) * kv;
        }
        #pragma unroll
        for (int off = 1; off < 16; off <<= 1) {
          sk2 += __shfl_xor(sk2, off, 64);
          sqk += __shfl_xor(sqk, off, 64);
        }
        if (lr16 == 0) {
          part[widN][r][0] = sk2;
          part[widN][r][1] = sqk;
        }
      }
    }
    __syncthreads();
    if (tid < 128) {
      int t = by * 128 + tid;
      int o = (t * 4 + g) * 4 + qq;
      kssP[o] = part[0][tid][0] + part[1][tid][0];
      qkP[o]  = part[0][tid][1] + part[1][tid][1];
    }
  } else {
    // ---- vraw tile: store bf16 V + per-row v^2 partial ----
    int q2i = bx - 16;
    #pragma unroll
    for (int m = 0; m < 4; ++m) {
      #pragma unroll
      for (int j = 0; j < 4; ++j) {
        int r = wm + m * 16 + rgrp * 4 + j;
        size_t t = (size_t)(by * 128 + r);
        float sv2 = 0.f;
        #pragma unroll
        for (int n = 0; n < 4; ++n) {
          float v = acc[m][n][j];
          sv2 += v * v;
          V[t * 512 + q2i * 128 + wn + n * 16 + lr16] = f2bf(v);
        }
        #pragma unroll
        for (int off = 1; off < 16; off <<= 1) sv2 += __shfl_xor(sv2, off, 64);
        if (lr16 == 0) part[widN][r][0] = sv2;
      }
    }
    __syncthreads();
    if (tid < 128) {
      int t = by * 128 + tid;
      msvP[t * 4 + q2i] = part[0][tid][0] + part[1][tid][0];
    }
  }
}

// ---------------- Kernel C1: finish gates from partials ---------------------
__global__ __launch_bounds__(256) void gate_finish(
    const float* __restrict__ kssP, const float* __restrict__ qkP,
    const float* __restrict__ qssA, const float* __restrict__ msvP,
    float* __restrict__ gateA, float* __restrict__ aA) {
  int i = blockIdx.x * 256 + threadIdx.x;          // T*4
  int t = i >> 2;
  float4 k4 = *(const float4*)&kssP[i * 4];
  float4 d4 = *(const float4*)&qkP[i * 4];
  float4 m4 = *(const float4*)&msvP[t * 4];
  float kss = k4.x + k4.y + k4.z + k4.w;
  float qk  = d4.x + d4.y + d4.z + d4.w;
  float qss = qssA[i];
  float msv = (m4.x + m4.y + m4.z + m4.w) * (1.0f / 512.0f);
  float qinv = rsqrtf(qss * (1.0f / 512.0f) + EPS_N);
  float kinv = rsqrtf(kss * (1.0f / 512.0f) + EPS_N);
  float gate = 1.0f / (1.0f + __expf(-qk * qinv * kinv * QK_SCALE));
  gateA[i] = gate;
  aA[i] = gate * rsqrtf(gate * gate * msv + EPS_N);
}

// ---------------- Kernel C2: value + dilated conv + silu + write out --------
__global__ __launch_bounds__(256) void out_kernel(
    const u16* __restrict__ V,          // (T,512) bf16
    const float* __restrict__ gateA, const float* __restrict__ aA,
    const float* __restrict__ wc,       // [4][2048]
    float* __restrict__ out) {
  int idx = blockIdx.x * 256 + threadIdx.x;  // T*256 threads, 8 ch each
  int t = idx >> 8;
  int c8 = (idx & 255) * 8;
  int g = c8 >> 9;
  int h = c8 & 511;

  float acc[8] = {0.f, 0.f, 0.f, 0.f, 0.f, 0.f, 0.f, 0.f};
  float vr_t[8];
  #pragma unroll
  for (int k = 0; k < 4; ++k) {
    int tk = t - 12 + 4 * k;
    if (tk < 0) continue;
    float s = aA[tk * 4 + g];
    u16x8 vv = *(const u16x8*)&V[(size_t)tk * 512 + h];
    float4 w0 = *(const float4*)(wc + k * 2048 + c8);
    float4 w1 = *(const float4*)(wc + k * 2048 + c8 + 4);
    float w8[8] = {w0.x, w0.y, w0.z, w0.w, w1.x, w1.y, w1.z, w1.w};
    #pragma unroll
    for (int j = 0; j < 8; ++j) {
      float v = bf2f(vv[j]);
      acc[j] += w8[j] * s * v;
      if (k == 3) vr_t[j] = v;
    }
  }
  float gate = gateA[t * 4 + g];
  float r[8];
  #pragma unroll
  for (int j = 0; j < 8; ++j) {
    float y = acc[j];
    r[j] = gate * vr_t[j] + y / (1.0f + __expf(-y));
  }
  float* op = out + (size_t)t * 2048 + c8;
  *(float4*)op       = make_float4(r[0], r[1], r[2], r[3]);
  *(float4*)(op + 4) = make_float4(r[4], r[5], r[6], r[7]);
}

extern "C" void kernel_launch(void* const* d_in, const int* in_sizes, int n_in,
                              void* d_out, int out_size, void* d_ws, size_t ws_size,
                              hipStream_t stream) {
  const int*   hash_ids = (const int*)d_in[0];
  const int*   offsets  = (const int*)d_in[1];
  const float* emb_w    = (const float*)d_in[2];
  const float* kp       = (const float*)d_in[3];
  const float* qw       = (const float*)d_in[4];
  const float* kw       = (const float*)d_in[5];
  const float* vp       = (const float*)d_in[6];
  const float* conv_w   = (const float*)d_in[7];
  const float* cw       = (const float*)d_in[8];
  const float* hidden   = (const float*)d_in[9];
  float* out = (float*)d_out;
  char*  ws  = (char*)d_ws;

  u16*   V     = (u16*)ws;                       // 16,777,216
  u16*   emb   = (u16*)(ws + 16777216);          // 25,165,824
  u16*   wt    = (u16*)(ws + 41943040);          //  3,932,160
  u16*   qhp   = (u16*)(ws + 45875200);          // 67,108,864
  float* kssP  = (float*)(ws + 112984064);       //  1,048,576
  float* qkP   = (float*)(ws + 114032640);       //  1,048,576
  float* qssA  = (float*)(ws + 115081216);       //    262,144
  float* msvP  = (float*)(ws + 115343360);       //    262,144
  float* gateA = (float*)(ws + 115605504);       //    262,144
  float* aA    = (float*)(ws + 115867648);       //    262,144
  float* wc    = (float*)(ws + 116129792);       //     32,768
  float* qwkw  = (float*)(ws + 116162560);       //      8,192

  gather_emb<<<(T_TOK * 12 * 8) / 256, 256, 0, stream>>>(hash_ids, offsets, emb_w, emb);
  build_wcat<<<dim3(16, 24, 5), dim3(32, 8), 0, stream>>>(kp, vp, wt);
  build_wc<<<8, 256, 0, stream>>>(conv_w, cw, qw, kw, wc, qwkw);
  prep_q<<<T_TOK, 256, 0, stream>>>(hidden, qwkw, qhp, qssA);
  gemm_bf16<<<dim3(20, 128), 256, 0, stream>>>(emb, wt, qhp, V, kssP, qkP, msvP);
  gate_finish<<<(T_TOK * 4) / 256, 256, 0, stream>>>(kssP, qkP, qssA, msvP, gateA, aA);
  out_kernel<<<T_TOK * 256 / 256, 256, 0, stream>>>(V, gateA, aA, wc, out);
}

// Round 6
// 196.275 us; speedup vs baseline: 1.0957x; 1.0463x over previous
//
#include <hip/hip_runtime.h>
#include <hip/hip_bf16.h>
#include <math.h>

#define T_TOK  16384
#define H_DIM  512
#define NHEADS 12
#define E_DIM  768
#define EPS_N  1e-5f
#define QK_SCALE 0.04419417382415922f

typedef unsigned short u16;
typedef __bf16 bf16;
typedef bf16   bf16x8 __attribute__((ext_vector_type(8)));
typedef float  f32x4  __attribute__((ext_vector_type(4)));
typedef u16    u16x4  __attribute__((ext_vector_type(4)));
typedef u16    u16x8  __attribute__((ext_vector_type(8)));

__device__ __forceinline__ u16 f2bf(float f) {
  unsigned u = __builtin_bit_cast(unsigned, f);
  unsigned r = u + 0x7fffu + ((u >> 16) & 1u);
  return (u16)(r >> 16);
}
__device__ __forceinline__ float bf2f(u16 h) {
  unsigned u = ((unsigned)h) << 16;
  return __builtin_bit_cast(float, u);
}
__device__ __forceinline__ float wave_sum(float v) {
  #pragma unroll
  for (int off = 32; off; off >>= 1) v += __shfl_xor(v, off, 64);
  return v;
}

// ---------------- Kernel A: gather embedding rows, cast to bf16 -------------
__global__ __launch_bounds__(256) void gather_emb(
    const int* __restrict__ hash_ids, const int* __restrict__ offsets,
    const float* __restrict__ emb_w, u16* __restrict__ emb) {
  int idx = blockIdx.x * 256 + threadIdx.x;        // T*12*8
  int pair = idx >> 3;                             // t*12 + head
  int sub = idx & 7;
  int t = pair / 12;
  int head = pair - t * 12;
  int row = hash_ids[pair] + offsets[head];
  const float* src = emb_w + (size_t)row * 64 + sub * 8;
  float4 a = *(const float4*)src;
  float4 b = *(const float4*)(src + 4);
  u16x8 o;
  o[0] = f2bf(a.x); o[1] = f2bf(a.y); o[2] = f2bf(a.z); o[3] = f2bf(a.w);
  o[4] = f2bf(b.x); o[5] = f2bf(b.y); o[6] = f2bf(b.z); o[7] = f2bf(b.w);
  *(u16x8*)(emb + (size_t)t * E_DIM + head * 64 + sub * 8) = o;
}

// ---------------- Kernel A2: build WcatT (2560 x 768) bf16 ------------------
__global__ __launch_bounds__(256) void build_wcat(
    const float* __restrict__ kp, const float* __restrict__ vp,
    u16* __restrict__ wt) {
  __shared__ float tile[32][33];
  int m = blockIdx.z;
  const float* src = (m < 4) ? (kp + (size_t)m * E_DIM * H_DIM) : vp;
  int h0 = blockIdx.x * 32, e0 = blockIdx.y * 32;
  int tx = threadIdx.x, ty = threadIdx.y;          // block (32,8)
  #pragma unroll
  for (int j = 0; j < 32; j += 8)
    tile[ty + j][tx] = src[(size_t)(e0 + ty + j) * H_DIM + h0 + tx];
  __syncthreads();
  #pragma unroll
  for (int j = 0; j < 32; j += 8) {
    int h = h0 + ty + j, e = e0 + tx;
    wt[(size_t)(m * H_DIM + h) * E_DIM + e] = f2bf(tile[tx][ty + j]);
  }
}

// ---------------- Kernel A3: fold conv_norm_w into conv w; qw*kw ------------
__global__ __launch_bounds__(256) void build_wc(
    const float* __restrict__ conv_w, const float* __restrict__ cnw,
    const float* __restrict__ qw, const float* __restrict__ kw,
    float* __restrict__ wc, float* __restrict__ qwkw) {
  int cf = blockIdx.x * 256 + threadIdx.x;         // 2048
  float c = cnw[cf];
  #pragma unroll
  for (int k = 0; k < 4; ++k) wc[k * 2048 + cf] = conv_w[cf * 4 + k] * c;
  qwkw[cf] = qw[cf] * kw[cf];
}

// ---------------- Kernel A4: prep q (vectorized, LDS permute) ---------------
// qhp[t*2048 + (c>>6)*64 + (c&15)*4 + ((c>>4)&3)] = bf16(hidden[t,c]*qw[c]*kw[c])
// qssA[t*4+g] = sum_{c in group g} hidden[t,c]^2   (fp32)
__global__ __launch_bounds__(256) void prep_q(
    const float* __restrict__ hidden, const float* __restrict__ qwkw,
    u16* __restrict__ qhp, float* __restrict__ qssA) {
  __shared__ u16 qs[32 * 72];                      // 72-stride pad: 2-way banks
  int t = blockIdx.x, tid = threadIdx.x;
  int b = tid >> 3;                                // 64-col block 0..31
  int c0 = tid * 8;
  const float* hp = hidden + (size_t)t * 2048 + c0;
  float4 a0 = *(const float4*)hp;
  float4 a1 = *(const float4*)(hp + 4);
  float4 w0 = *(const float4*)(qwkw + c0);
  float4 w1 = *(const float4*)(qwkw + c0 + 4);
  float q[8] = {a0.x, a0.y, a0.z, a0.w, a1.x, a1.y, a1.z, a1.w};
  float w[8] = {w0.x, w0.y, w0.z, w0.w, w1.x, w1.y, w1.z, w1.w};
  float q2 = 0.f;
  u16x8 v;
  #pragma unroll
  for (int j = 0; j < 8; ++j) { q2 += q[j] * q[j]; v[j] = f2bf(q[j] * w[j]); }
  *(u16x8*)&qs[b * 72 + (c0 & 63)] = v;
  q2 = wave_sum(q2);
  if ((tid & 63) == 0) qssA[t * 4 + (tid >> 6)] = q2;
  __syncthreads();
  int r0 = (c0 & 63) >> 2;                         // base slot>>2
  u16x8 o;
  #pragma unroll
  for (int half = 0; half < 2; ++half)
    #pragma unroll
    for (int j = 0; j < 4; ++j)
      o[half * 4 + j] = qs[b * 72 + j * 16 + r0 + half];
  *(u16x8*)(qhp + (size_t)t * 2048 + c0) = o;
}

// ---------------- Kernel B: GEMM + fused k-side reduction epilogue ----------
// Staging LDS (As/Bs, 32 KB) is reused after the K-loop as reduction scratch.
__global__ __launch_bounds__(256, 2) void gemm_bf16(
    const u16* __restrict__ A, const u16* __restrict__ BT,
    const u16* __restrict__ qhp,
    u16* __restrict__ V, float* __restrict__ kssP, float* __restrict__ qkP,
    float* __restrict__ msvP) {
  __shared__ char smem[32768];
  u16 (*As)[64] = (u16(*)[64])smem;                // [128][64]
  u16 (*Bs)[64] = (u16(*)[64])(smem + 16384);      // [128][64]
  float2* red2 = (float2*)smem;                    // [(widN*128+r)*16 + lr16]
  float*  red1 = (float*)smem;                     // [(widN*128+r)*16 + lr16]
  const int K = E_DIM;
  int tid = threadIdx.x;
  int lane = tid & 63, wid = tid >> 6;
  int bx = blockIdx.x, by = blockIdx.y;
  int wm = (wid >> 1) * 64, wn = (wid & 1) * 64;
  int widN = wid & 1;
  int lr16 = lane & 15, rgrp = lane >> 4;

  const u16* aptr = A + (size_t)(by * 128 + (tid >> 3)) * K + (tid & 7) * 8;
  const u16* bptr = BT + (size_t)(bx * 128 + (tid >> 3)) * K + (tid & 7) * 8;
  int lds_off = tid * 16;

  f32x4 acc[4][4] = {};

  for (int k0 = 0; k0 < K; k0 += 64) {
    #pragma unroll
    for (int r = 0; r < 4; ++r) {
      __builtin_amdgcn_global_load_lds(
        (const __attribute__((address_space(1))) void*)(aptr + (size_t)(r * 32) * K + k0),
        (__attribute__((address_space(3))) void*)(smem + r * 4096 + lds_off),
        16, 0, 0);
      __builtin_amdgcn_global_load_lds(
        (const __attribute__((address_space(1))) void*)(bptr + (size_t)(r * 32) * K + k0),
        (__attribute__((address_space(3))) void*)(smem + 16384 + r * 4096 + lds_off),
        16, 0, 0);
    }
    __syncthreads();
    int lk8 = (lane >> 4) * 8;
    #pragma unroll
    for (int kk = 0; kk < 2; ++kk) {
      bf16x8 af[4], bfv[4];
      #pragma unroll
      for (int m = 0; m < 4; ++m)
        af[m] = *reinterpret_cast<const bf16x8*>(&As[wm + m * 16 + lr16][kk * 32 + lk8]);
      #pragma unroll
      for (int n = 0; n < 4; ++n)
        bfv[n] = *reinterpret_cast<const bf16x8*>(&Bs[wn + n * 16 + lr16][kk * 32 + lk8]);
      #pragma unroll
      for (int m = 0; m < 4; ++m)
        #pragma unroll
        for (int n = 0; n < 4; ++n)
          acc[m][n] = __builtin_amdgcn_mfma_f32_16x16x32_bf16(af[m], bfv[n], acc[m][n], 0, 0, 0);
    }
    __syncthreads();
  }
  // K-loop done; all waves past final barrier -> staging LDS reusable.

  if (bx < 16) {
    // ---- key tile: local n-sums -> LDS transpose -> 128-thread reduce ----
    int g = bx >> 2, qq = bx & 3;
    int cb = (g * 8 + qq * 2 + (wn >> 6)) * 64 + lr16 * 4;
    u16x4 qf[4][4];
    #pragma unroll
    for (int m = 0; m < 4; ++m)
      #pragma unroll
      for (int j = 0; j < 4; ++j)
        qf[m][j] = *(const u16x4*)(qhp +
            (size_t)(by * 128 + wm + m * 16 + rgrp * 4 + j) * 2048 + cb);
    #pragma unroll
    for (int m = 0; m < 4; ++m) {
      #pragma unroll
      for (int j = 0; j < 4; ++j) {
        int r = wm + m * 16 + rgrp * 4 + j;        // block-local row
        float sk2 = 0.f, sqk = 0.f;
        #pragma unroll
        for (int n = 0; n < 4; ++n) {
          float kv = acc[m][n][j];
          sk2 += kv * kv;
          sqk += bf2f(qf[m][j][n]) * kv;
        }
        red2[(widN * 128 + r) * 16 + lr16] = make_float2(sk2, sqk);
      }
    }
    __syncthreads();
    if (tid < 128) {
      float s0 = 0.f, s1 = 0.f;
      #pragma unroll
      for (int j = 0; j < 16; ++j) {
        int jj = (j + tid) & 15;
        float2 a = red2[tid * 16 + jj];
        float2 b = red2[(128 + tid) * 16 + jj];
        s0 += a.x + b.x;
        s1 += a.y + b.y;
      }
      int t = by * 128 + tid;
      int o = (t * 4 + g) * 4 + qq;
      kssP[o] = s0;
      qkP[o]  = s1;
    }
  } else {
    // ---- vraw tile: store bf16 V + per-row v^2 via LDS transpose ----
    int q2i = bx - 16;
    #pragma unroll
    for (int m = 0; m < 4; ++m) {
      #pragma unroll
      for (int j = 0; j < 4; ++j) {
        int r = wm + m * 16 + rgrp * 4 + j;
        size_t t = (size_t)(by * 128 + r);
        float sv2 = 0.f;
        #pragma unroll
        for (int n = 0; n < 4; ++n) {
          float v = acc[m][n][j];
          sv2 += v * v;
          V[t * 512 + q2i * 128 + wn + n * 16 + lr16] = f2bf(v);
        }
        red1[(widN * 128 + r) * 16 + lr16] = sv2;
      }
    }
    __syncthreads();
    if (tid < 128) {
      float s = 0.f;
      #pragma unroll
      for (int j = 0; j < 16; ++j) {
        int jj = (j + tid) & 15;
        s += red1[tid * 16 + jj] + red1[(128 + tid) * 16 + jj];
      }
      int t = by * 128 + tid;
      msvP[t * 4 + q2i] = s;
    }
  }
}

// ---------------- Kernel C1: finish gates from partials ---------------------
__global__ __launch_bounds__(256) void gate_finish(
    const float* __restrict__ kssP, const float* __restrict__ qkP,
    const float* __restrict__ qssA, const float* __restrict__ msvP,
    float* __restrict__ gateA, float* __restrict__ aA) {
  int i = blockIdx.x * 256 + threadIdx.x;          // T*4
  int t = i >> 2;
  float4 k4 = *(const float4*)&kssP[i * 4];
  float4 d4 = *(const float4*)&qkP[i * 4];
  float4 m4 = *(const float4*)&msvP[t * 4];
  float kss = k4.x + k4.y + k4.z + k4.w;
  float qk  = d4.x + d4.y + d4.z + d4.w;
  float qss = qssA[i];
  float msv = (m4.x + m4.y + m4.z + m4.w) * (1.0f / 512.0f);
  float qinv = rsqrtf(qss * (1.0f / 512.0f) + EPS_N);
  float kinv = rsqrtf(kss * (1.0f / 512.0f) + EPS_N);
  float gate = 1.0f / (1.0f + __expf(-qk * qinv * kinv * QK_SCALE));
  gateA[i] = gate;
  aA[i] = gate * rsqrtf(gate * gate * msv + EPS_N);
}

// ---------------- Kernel C2: value + dilated conv + silu + write out --------
__global__ __launch_bounds__(256) void out_kernel(
    const u16* __restrict__ V,          // (T,512) bf16
    const float* __restrict__ gateA, const float* __restrict__ aA,
    const float* __restrict__ wc,       // [4][2048]
    float* __restrict__ out) {
  int idx = blockIdx.x * 256 + threadIdx.x;  // T*256 threads, 8 ch each
  int t = idx >> 8;
  int c8 = (idx & 255) * 8;
  int g = c8 >> 9;
  int h = c8 & 511;

  float acc[8] = {0.f, 0.f, 0.f, 0.f, 0.f, 0.f, 0.f, 0.f};
  float vr_t[8];
  #pragma unroll
  for (int k = 0; k < 4; ++k) {
    int tk = t - 12 + 4 * k;
    if (tk < 0) continue;
    float s = aA[tk * 4 + g];
    u16x8 vv = *(const u16x8*)&V[(size_t)tk * 512 + h];
    float4 w0 = *(const float4*)(wc + k * 2048 + c8);
    float4 w1 = *(const float4*)(wc + k * 2048 + c8 + 4);
    float w8[8] = {w0.x, w0.y, w0.z, w0.w, w1.x, w1.y, w1.z, w1.w};
    #pragma unroll
    for (int j = 0; j < 8; ++j) {
      float v = bf2f(vv[j]);
      acc[j] += w8[j] * s * v;
      if (k == 3) vr_t[j] = v;
    }
  }
  float gate = gateA[t * 4 + g];
  float r[8];
  #pragma unroll
  for (int j = 0; j < 8; ++j) {
    float y = acc[j];
    r[j] = gate * vr_t[j] + y / (1.0f + __expf(-y));
  }
  float* op = out + (size_t)t * 2048 + c8;
  *(float4*)op       = make_float4(r[0], r[1], r[2], r[3]);
  *(float4*)(op + 4) = make_float4(r[4], r[5], r[6], r[7]);
}

extern "C" void kernel_launch(void* const* d_in, const int* in_sizes, int n_in,
                              void* d_out, int out_size, void* d_ws, size_t ws_size,
                              hipStream_t stream) {
  const int*   hash_ids = (const int*)d_in[0];
  const int*   offsets  = (const int*)d_in[1];
  const float* emb_w    = (const float*)d_in[2];
  const float* kp       = (const float*)d_in[3];
  const float* qw       = (const float*)d_in[4];
  const float* kw       = (const float*)d_in[5];
  const float* vp       = (const float*)d_in[6];
  const float* conv_w   = (const float*)d_in[7];
  const float* cw       = (const float*)d_in[8];
  const float* hidden   = (const float*)d_in[9];
  float* out = (float*)d_out;
  char*  ws  = (char*)d_ws;

  u16*   V     = (u16*)ws;                       // 16,777,216
  u16*   emb   = (u16*)(ws + 16777216);          // 25,165,824
  u16*   wt    = (u16*)(ws + 41943040);          //  3,932,160
  u16*   qhp   = (u16*)(ws + 45875200);          // 67,108,864
  float* kssP  = (float*)(ws + 112984064);       //  1,048,576
  float* qkP   = (float*)(ws + 114032640);       //  1,048,576
  float* qssA  = (float*)(ws + 115081216);       //    262,144
  float* msvP  = (float*)(ws + 115343360);       //    262,144
  float* gateA = (float*)(ws + 115605504);       //    262,144
  float* aA    = (float*)(ws + 115867648);       //    262,144
  float* wc    = (float*)(ws + 116129792);       //     32,768
  float* qwkw  = (float*)(ws + 116162560);       //      8,192

  gather_emb<<<(T_TOK * 12 * 8) / 256, 256, 0, stream>>>(hash_ids, offsets, emb_w, emb);
  build_wcat<<<dim3(16, 24, 5), dim3(32, 8), 0, stream>>>(kp, vp, wt);
  build_wc<<<8, 256, 0, stream>>>(conv_w, cw, qw, kw, wc, qwkw);
  prep_q<<<T_TOK, 256, 0, stream>>>(hidden, qwkw, qhp, qssA);
  gemm_bf16<<<dim3(20, 128), 256, 0, stream>>>(emb, wt, qhp, V, kssP, qkP, msvP);
  gate_finish<<<(T_TOK * 4) / 256, 256, 0, stream>>>(kssP, qkP, qssA, msvP, gateA, aA);
  out_kernel<<<T_TOK * 256 / 256, 256, 0, stream>>>(V, gateA, aA, wc, out);
}

// Round 7
// 183.995 us; speedup vs baseline: 1.1689x; 1.0667x over previous
//
#include <hip/hip_runtime.h>
#include <hip/hip_bf16.h>
#include <math.h>

#define T_TOK  16384
#define H_DIM  512
#define NHEADS 12
#define E_DIM  768
#define EPS_N  1e-5f
#define QK_SCALE 0.04419417382415922f

typedef unsigned short u16;
typedef __bf16 bf16;
typedef bf16   bf16x8 __attribute__((ext_vector_type(8)));
typedef float  f32x4  __attribute__((ext_vector_type(4)));
typedef u16    u16x4  __attribute__((ext_vector_type(4)));
typedef u16    u16x8  __attribute__((ext_vector_type(8)));

__device__ __forceinline__ u16 f2bf(float f) {
  unsigned u = __builtin_bit_cast(unsigned, f);
  unsigned r = u + 0x7fffu + ((u >> 16) & 1u);
  return (u16)(r >> 16);
}
__device__ __forceinline__ float bf2f(u16 h) {
  unsigned u = ((unsigned)h) << 16;
  return __builtin_bit_cast(float, u);
}

// ---------------- Kernel A: gather embedding rows, cast to bf16 -------------
__global__ __launch_bounds__(256) void gather_emb(
    const int* __restrict__ hash_ids, const int* __restrict__ offsets,
    const float* __restrict__ emb_w, u16* __restrict__ emb) {
  int idx = blockIdx.x * 256 + threadIdx.x;        // T*12*8
  int pair = idx >> 3;                             // t*12 + head
  int sub = idx & 7;
  int t = pair / 12;
  int head = pair - t * 12;
  int row = hash_ids[pair] + offsets[head];
  const float* src = emb_w + (size_t)row * 64 + sub * 8;
  float4 a = *(const float4*)src;
  float4 b = *(const float4*)(src + 4);
  u16x8 o;
  o[0] = f2bf(a.x); o[1] = f2bf(a.y); o[2] = f2bf(a.z); o[3] = f2bf(a.w);
  o[4] = f2bf(b.x); o[5] = f2bf(b.y); o[6] = f2bf(b.z); o[7] = f2bf(b.w);
  *(u16x8*)(emb + (size_t)t * E_DIM + head * 64 + sub * 8) = o;
}

// ---------------- Kernel A2: build WcatT (2560 x 768) bf16 ------------------
__global__ __launch_bounds__(256) void build_wcat(
    const float* __restrict__ kp, const float* __restrict__ vp,
    u16* __restrict__ wt) {
  __shared__ float tile[32][33];
  int m = blockIdx.z;
  const float* src = (m < 4) ? (kp + (size_t)m * E_DIM * H_DIM) : vp;
  int h0 = blockIdx.x * 32, e0 = blockIdx.y * 32;
  int tx = threadIdx.x, ty = threadIdx.y;          // block (32,8)
  #pragma unroll
  for (int j = 0; j < 32; j += 8)
    tile[ty + j][tx] = src[(size_t)(e0 + ty + j) * H_DIM + h0 + tx];
  __syncthreads();
  #pragma unroll
  for (int j = 0; j < 32; j += 8) {
    int h = h0 + ty + j, e = e0 + tx;
    wt[(size_t)(m * H_DIM + h) * E_DIM + e] = f2bf(tile[tx][ty + j]);
  }
}

// ---------------- Kernel A3: fold conv_norm_w into conv w; qw*kw ------------
__global__ __launch_bounds__(256) void build_wc(
    const float* __restrict__ conv_w, const float* __restrict__ cnw,
    const float* __restrict__ qw, const float* __restrict__ kw,
    float* __restrict__ wc, float* __restrict__ qwkw) {
  int cf = blockIdx.x * 256 + threadIdx.x;         // 2048
  float c = cnw[cf];
  #pragma unroll
  for (int k = 0; k < 4; ++k) wc[k * 2048 + cf] = conv_w[cf * 4 + k] * c;
  qwkw[cf] = qw[cf] * kw[cf];
}

// ---------------- Kernel B: GEMM + fully fused gate-side epilogue -----------
// C = A(16384x768) * BT^T. Key tiles (bx<16): stage own hidden quarter to LDS
// (bf16), compute qss (fp32, during staging), sk2/sqk reductions -> partials.
// vraw tiles (bx>=16): store V bf16 + per-row v^2 partial.
__global__ __launch_bounds__(256, 2) void gemm_bf16(
    const u16* __restrict__ A, const u16* __restrict__ BT,
    const float* __restrict__ hidden, const float* __restrict__ qwkw,
    u16* __restrict__ V, float* __restrict__ kssP, float* __restrict__ qkP,
    float* __restrict__ qssP, float* __restrict__ msvP) {
  __shared__ __align__(16) char smem[50176];
  u16 (*As)[64] = (u16(*)[64])smem;                // [128][64]
  u16 (*Bs)[64] = (u16(*)[64])(smem + 16384);      // [128][64]
  u16*    qlds  = (u16*)smem;                      // [128][132] bf16 (epilogue)
  float2* red2h = (float2*)(smem + 33792);         // [2][128][8]
  float*  red1  = (float*)smem;                    // [2][128][16] (vraw path)
  const int K = E_DIM;
  int tid = threadIdx.x;
  int lane = tid & 63, wid = tid >> 6;

  // bijective XCD swizzle: 2560 blocks % 8 == 0
  int orig = blockIdx.x + blockIdx.y * 20;
  int swz = (orig & 7) * 320 + (orig >> 3);
  int bx = swz % 20, by = swz / 20;

  int wm = (wid >> 1) * 64, wn = (wid & 1) * 64;
  int widN = wid & 1;
  int lr16 = lane & 15, rgrp = lane >> 4;

  const u16* aptr = A + (size_t)(by * 128 + (tid >> 3)) * K + (tid & 7) * 8;
  const u16* bptr = BT + (size_t)(bx * 128 + (tid >> 3)) * K + (tid & 7) * 8;
  int lds_off = tid * 16;

  f32x4 acc[4][4] = {};

  for (int k0 = 0; k0 < K; k0 += 64) {
    #pragma unroll
    for (int r = 0; r < 4; ++r) {
      __builtin_amdgcn_global_load_lds(
        (const __attribute__((address_space(1))) void*)(aptr + (size_t)(r * 32) * K + k0),
        (__attribute__((address_space(3))) void*)(smem + r * 4096 + lds_off),
        16, 0, 0);
      __builtin_amdgcn_global_load_lds(
        (const __attribute__((address_space(1))) void*)(bptr + (size_t)(r * 32) * K + k0),
        (__attribute__((address_space(3))) void*)(smem + 16384 + r * 4096 + lds_off),
        16, 0, 0);
    }
    __syncthreads();
    int lk8 = (lane >> 4) * 8;
    #pragma unroll
    for (int kk = 0; kk < 2; ++kk) {
      bf16x8 af[4], bfv[4];
      #pragma unroll
      for (int m = 0; m < 4; ++m)
        af[m] = *reinterpret_cast<const bf16x8*>(&As[wm + m * 16 + lr16][kk * 32 + lk8]);
      #pragma unroll
      for (int n = 0; n < 4; ++n)
        bfv[n] = *reinterpret_cast<const bf16x8*>(&Bs[wn + n * 16 + lr16][kk * 32 + lk8]);
      #pragma unroll
      for (int m = 0; m < 4; ++m)
        #pragma unroll
        for (int n = 0; n < 4; ++n)
          acc[m][n] = __builtin_amdgcn_mfma_f32_16x16x32_bf16(af[m], bfv[n], acc[m][n], 0, 0, 0);
    }
    __syncthreads();
  }
  // K-loop done; all waves past final barrier -> staging LDS reusable.

  if (bx < 16) {
    int g = bx >> 2, qq = bx & 3;
    // ---- stage hidden quarter (128x128 fp32 -> bf16 LDS), qss on the fly ---
    const float* hq = hidden + (size_t)(by * 128) * 2048 + g * 512 + qq * 128;
    float s2[8];
    #pragma unroll
    for (int p = 0; p < 8; ++p) {
      int row = p * 16 + (tid >> 4);
      int col = (tid & 15) * 8;
      const float* src = hq + (size_t)row * 2048 + col;
      float4 x0 = *(const float4*)src;
      float4 x1 = *(const float4*)(src + 4);
      float qv[8] = {x0.x, x0.y, x0.z, x0.w, x1.x, x1.y, x1.z, x1.w};
      u16x8 o;
      float ss = 0.f;
      #pragma unroll
      for (int j = 0; j < 8; ++j) { ss += qv[j] * qv[j]; o[j] = f2bf(qv[j]); }
      s2[p] = ss;
      *(u16x8*)&qlds[row * 132 + col] = o;
    }
    #pragma unroll
    for (int off = 1; off < 16; off <<= 1)
      #pragma unroll
      for (int p = 0; p < 8; ++p) s2[p] += __shfl_xor(s2[p], off, 64);
    if ((tid & 15) == 0) {
      #pragma unroll
      for (int p = 0; p < 8; ++p) {
        int t = by * 128 + p * 16 + (tid >> 4);
        qssP[(t * 4 + g) * 4 + qq] = s2[p];
      }
    }
    __syncthreads();

    // ---- per-thread k-side sums, 1 shfl pre-reduce, LDS transpose ----
    int colg = g * 512 + qq * 128 + wn + lr16;
    float w4[4];
    #pragma unroll
    for (int n = 0; n < 4; ++n) w4[n] = qwkw[colg + n * 16];
    #pragma unroll
    for (int m = 0; m < 4; ++m) {
      #pragma unroll
      for (int j = 0; j < 4; ++j) {
        int r = wm + m * 16 + rgrp * 4 + j;        // block-local row
        float sk2 = 0.f, sqk = 0.f;
        #pragma unroll
        for (int n = 0; n < 4; ++n) {
          float kv = acc[m][n][j];
          float qv = bf2f(qlds[r * 132 + wn + n * 16 + lr16]);
          sk2 += kv * kv;
          sqk += qv * w4[n] * kv;
        }
        sk2 += __shfl_xor(sk2, 8, 64);
        sqk += __shfl_xor(sqk, 8, 64);
        if (lr16 < 8) red2h[(widN * 128 + r) * 8 + lr16] = make_float2(sk2, sqk);
      }
    }
    __syncthreads();
    if (tid < 128) {
      float s0 = 0.f, s1 = 0.f;
      #pragma unroll
      for (int j = 0; j < 8; ++j) {
        int jj = (j + tid) & 7;
        float2 a = red2h[tid * 8 + jj];
        float2 b = red2h[(128 + tid) * 8 + jj];
        s0 += a.x + b.x;
        s1 += a.y + b.y;
      }
      int t = by * 128 + tid;
      int o = (t * 4 + g) * 4 + qq;
      kssP[o] = s0;
      qkP[o]  = s1;
    }
  } else {
    // ---- vraw tile: store bf16 V + per-row v^2 via LDS transpose ----
    int q2i = bx - 16;
    #pragma unroll
    for (int m = 0; m < 4; ++m) {
      #pragma unroll
      for (int j = 0; j < 4; ++j) {
        int r = wm + m * 16 + rgrp * 4 + j;
        size_t t = (size_t)(by * 128 + r);
        float sv2 = 0.f;
        #pragma unroll
        for (int n = 0; n < 4; ++n) {
          float v = acc[m][n][j];
          sv2 += v * v;
          V[t * 512 + q2i * 128 + wn + n * 16 + lr16] = f2bf(v);
        }
        red1[(widN * 128 + r) * 16 + lr16] = sv2;
      }
    }
    __syncthreads();
    if (tid < 128) {
      float s = 0.f;
      #pragma unroll
      for (int j = 0; j < 16; ++j) {
        int jj = (j + tid) & 15;
        s += red1[tid * 16 + jj] + red1[(128 + tid) * 16 + jj];
      }
      int t = by * 128 + tid;
      msvP[t * 4 + q2i] = s;
    }
  }
}

// ---------------- Kernel C1: finish gates from partials ---------------------
__global__ __launch_bounds__(256) void gate_finish(
    const float* __restrict__ kssP, const float* __restrict__ qkP,
    const float* __restrict__ qssP, const float* __restrict__ msvP,
    float* __restrict__ gateA, float* __restrict__ aA) {
  int i = blockIdx.x * 256 + threadIdx.x;          // T*4
  int t = i >> 2;
  float4 k4 = *(const float4*)&kssP[i * 4];
  float4 d4 = *(const float4*)&qkP[i * 4];
  float4 q4 = *(const float4*)&qssP[i * 4];
  float4 m4 = *(const float4*)&msvP[t * 4];
  float kss = k4.x + k4.y + k4.z + k4.w;
  float qk  = d4.x + d4.y + d4.z + d4.w;
  float qss = q4.x + q4.y + q4.z + q4.w;
  float msv = (m4.x + m4.y + m4.z + m4.w) * (1.0f / 512.0f);
  float qinv = rsqrtf(qss * (1.0f / 512.0f) + EPS_N);
  float kinv = rsqrtf(kss * (1.0f / 512.0f) + EPS_N);
  float gate = 1.0f / (1.0f + __expf(-qk * qinv * kinv * QK_SCALE));
  gateA[i] = gate;
  aA[i] = gate * rsqrtf(gate * gate * msv + EPS_N);
}

// ---------------- Kernel C2: value + dilated conv + silu + write out --------
__global__ __launch_bounds__(256) void out_kernel(
    const u16* __restrict__ V,          // (T,512) bf16
    const float* __restrict__ gateA, const float* __restrict__ aA,
    const float* __restrict__ wc,       // [4][2048]
    float* __restrict__ out) {
  int idx = blockIdx.x * 256 + threadIdx.x;  // T*256 threads, 8 ch each
  int t = idx >> 8;
  int c8 = (idx & 255) * 8;
  int g = c8 >> 9;
  int h = c8 & 511;

  float acc[8] = {0.f, 0.f, 0.f, 0.f, 0.f, 0.f, 0.f, 0.f};
  float vr_t[8];
  #pragma unroll
  for (int k = 0; k < 4; ++k) {
    int tk = t - 12 + 4 * k;
    if (tk < 0) continue;
    float s = aA[tk * 4 + g];
    u16x8 vv = *(const u16x8*)&V[(size_t)tk * 512 + h];
    float4 w0 = *(const float4*)(wc + k * 2048 + c8);
    float4 w1 = *(const float4*)(wc + k * 2048 + c8 + 4);
    float w8[8] = {w0.x, w0.y, w0.z, w0.w, w1.x, w1.y, w1.z, w1.w};
    #pragma unroll
    for (int j = 0; j < 8; ++j) {
      float v = bf2f(vv[j]);
      acc[j] += w8[j] * s * v;
      if (k == 3) vr_t[j] = v;
    }
  }
  float gate = gateA[t * 4 + g];
  float r[8];
  #pragma unroll
  for (int j = 0; j < 8; ++j) {
    float y = acc[j];
    r[j] = gate * vr_t[j] + y / (1.0f + __expf(-y));
  }
  float* op = out + (size_t)t * 2048 + c8;
  *(float4*)op       = make_float4(r[0], r[1], r[2], r[3]);
  *(float4*)(op + 4) = make_float4(r[4], r[5], r[6], r[7]);
}

extern "C" void kernel_launch(void* const* d_in, const int* in_sizes, int n_in,
                              void* d_out, int out_size, void* d_ws, size_t ws_size,
                              hipStream_t stream) {
  const int*   hash_ids = (const int*)d_in[0];
  const int*   offsets  = (const int*)d_in[1];
  const float* emb_w    = (const float*)d_in[2];
  const float* kp       = (const float*)d_in[3];
  const float* qw       = (const float*)d_in[4];
  const float* kw       = (const float*)d_in[5];
  const float* vp       = (const float*)d_in[6];
  const float* conv_w   = (const float*)d_in[7];
  const float* cw       = (const float*)d_in[8];
  const float* hidden   = (const float*)d_in[9];
  float* out = (float*)d_out;
  char*  ws  = (char*)d_ws;

  u16*   V     = (u16*)ws;                       // 16,777,216
  u16*   emb   = (u16*)(ws + 16777216);          // 25,165,824
  u16*   wt    = (u16*)(ws + 41943040);          //  3,932,160
  float* kssP  = (float*)(ws + 45875200);        //  1,048,576
  float* qkP   = (float*)(ws + 46923776);        //  1,048,576
  float* qssP  = (float*)(ws + 47972352);        //  1,048,576
  float* msvP  = (float*)(ws + 49020928);        //    262,144
  float* gateA = (float*)(ws + 49283072);        //    262,144
  float* aA    = (float*)(ws + 49545216);        //    262,144
  float* wc    = (float*)(ws + 49807360);        //     32,768
  float* qwkw  = (float*)(ws + 49840128);        //      8,192

  gather_emb<<<(T_TOK * 12 * 8) / 256, 256, 0, stream>>>(hash_ids, offsets, emb_w, emb);
  build_wcat<<<dim3(16, 24, 5), dim3(32, 8), 0, stream>>>(kp, vp, wt);
  build_wc<<<8, 256, 0, stream>>>(conv_w, cw, qw, kw, wc, qwkw);
  gemm_bf16<<<dim3(20, 128), 256, 0, stream>>>(emb, wt, hidden, qwkw,
                                               V, kssP, qkP, qssP, msvP);
  gate_finish<<<(T_TOK * 4) / 256, 256, 0, stream>>>(kssP, qkP, qssP, msvP, gateA, aA);
  out_kernel<<<T_TOK * 256 / 256, 256, 0, stream>>>(V, gateA, aA, wc, out);
}